// Round 8
// baseline (384.355 us; speedup 1.0000x reference)
//
#include <hip/hip_runtime.h>
#include <hip/hip_cooperative_groups.h>

#define N_TOK 4096
#define D_IN  512
#define D_HID 256
#define N_OUT 40

typedef _Float16 half8 __attribute__((ext_vector_type(8)));
typedef _Float16 half4 __attribute__((ext_vector_type(4)));
typedef float    f32x4 __attribute__((ext_vector_type(4)));

// async 16B/lane global->LDS DMA; lds dst is wave-uniform base (+lane*16 implicit)
__device__ __forceinline__ void async_copy16(const _Float16* g, _Float16* l) {
  __builtin_amdgcn_global_load_lds(
      (const __attribute__((address_space(1))) unsigned int*)(g),
      (__attribute__((address_space(3))) unsigned int*)(l), 16, 0, 0);
}

struct Params {
  const float *adj, *h, *Wq, *bq, *Wk, *bk, *Wv, *bv, *Wo, *bo, *gamma, *beta, *Wp, *bp;
  float* out;
  char* ws;
};

// workspace offsets (bytes). Op overlays h16/Wqt/Wkt/Wvt (dead after P1).
#define OFF_WOT   0u
#define OFF_WPT   524288u
#define OFF_Q16   573440u
#define OFF_K16   4767744u
#define OFF_VT16  8962048u
#define OFF_LP    13156352u
#define OFF_OP    13418496u
#define OFF_H16   13418496u
#define OFF_WQT   17612800u
#define OFF_WKT   18137088u
#define OFF_WVT   18661376u

// phase: -1 = all phases with grid.sync (cooperative); 0..3 = single phase.
// launch_bounds(512,1): VGPR cap 256 (512-thr block = 2 waves/SIMD min) --
// attn phase needs ~216; (512,2) capped at 128 and spilled acc to scratch (R7).
__global__ __launch_bounds__(512, 1) void fused_kernel(Params P, int phase)
{
  __shared__ __align__(16) char smem[152576];
  const int bid = blockIdx.x, tid = threadIdx.x;
  const int w = tid >> 6, lane = tid & 63, quad = lane >> 4, cL = lane & 15;
  const int l5 = lane >> 5, l31 = lane & 31, l3h = lane >> 3, l7 = lane & 7;
  const f32x4 z4 = {0.f, 0.f, 0.f, 0.f};

  char* ws = P.ws;
  _Float16* Wot  = (_Float16*)(ws + OFF_WOT);
  _Float16* Wpt  = (_Float16*)(ws + OFF_WPT);
  _Float16* Q16  = (_Float16*)(ws + OFF_Q16);
  _Float16* K16  = (_Float16*)(ws + OFF_K16);
  _Float16* VT16 = (_Float16*)(ws + OFF_VT16);
  float*    Lp   = (float*)   (ws + OFF_LP);
  _Float16* Op   = (_Float16*)(ws + OFF_OP);
  _Float16* h16  = (_Float16*)(ws + OFF_H16);
  _Float16* Wqt  = (_Float16*)(ws + OFF_WQT);
  _Float16* Wkt  = (_Float16*)(ws + OFF_WKT);
  _Float16* Wvt  = (_Float16*)(ws + OFF_WVT);

  // ===================== P0: prep (grid-stride, 780 jobs) ====================
  if (phase <= 0) {
    float* lds = (float*)smem;
    for (int job = bid; job < 780; job += 256) {
      if (job < 512) {                         // h -> h16 (4096x512)
        int base = job * 4096 + tid * 8;
        float4 x0 = *(const float4*)(P.h + base);
        float4 x1 = *(const float4*)(P.h + base + 4);
        half8 o;
        o[0]=(_Float16)x0.x; o[1]=(_Float16)x0.y; o[2]=(_Float16)x0.z; o[3]=(_Float16)x0.w;
        o[4]=(_Float16)x1.x; o[5]=(_Float16)x1.y; o[6]=(_Float16)x1.z; o[7]=(_Float16)x1.w;
        *(half8*)(h16 + base) = o;
      } else if (job < 768) {                  // W transposes via 64x64 LDS tile
        const float* src; _Float16* dst; int in_nc, i0, d0;
        if (job < 704) {                       // Wq/Wk/Wv: 6 mats x 32 tiles
          int t = job - 512;
          int mat = t >> 5;
          int m = mat >> 1, head = mat & 1;
          src = (m==0 ? P.Wq : (m==1 ? P.Wk : P.Wv)) + head * (D_IN * D_HID);
          dst = (m==0 ? Wqt : (m==1 ? Wkt : Wvt)) + head * (D_IN * D_HID);
          in_nc = D_HID;
          int tt = t & 31;
          i0 = (tt >> 2) * 64; d0 = (tt & 3) * 64;
        } else {                               // Wo: 64 tiles
          int t = job - 704;
          src = P.Wo; dst = Wot; in_nc = D_IN;
          i0 = (t >> 3) * 64; d0 = (t & 7) * 64;
        }
        int ii = tid >> 3, c8 = (tid & 7) * 8;
        float4 x0 = *(const float4*)(src + (size_t)(i0 + ii) * in_nc + d0 + c8);
        float4 x1 = *(const float4*)(src + (size_t)(i0 + ii) * in_nc + d0 + c8 + 4);
        lds[(c8 + 0) * 65 + ii] = x0.x;
        lds[(c8 + 1) * 65 + ii] = x0.y;
        lds[(c8 + 2) * 65 + ii] = x0.z;
        lds[(c8 + 3) * 65 + ii] = x0.w;
        lds[(c8 + 4) * 65 + ii] = x1.x;
        lds[(c8 + 5) * 65 + ii] = x1.y;
        lds[(c8 + 6) * 65 + ii] = x1.z;
        lds[(c8 + 7) * 65 + ii] = x1.w;
        __syncthreads();
        int dd = tid >> 3, ch = tid & 7;
        half8 o;
#pragma unroll
        for (int j = 0; j < 8; j++) o[j] = (_Float16)lds[dd * 65 + ch * 8 + j];
        *(half8*)(dst + (size_t)(d0 + dd) * D_IN + i0 + ch * 8) = o;
      } else {                                 // Wp transpose+pad [48][512]
        int t = job - 768;                     // 0..11
        int idx = t * 2048 + tid * 4;
        int j = idx >> 9, i = idx & 511;
        half4 o;
#pragma unroll
        for (int u = 0; u < 4; u++)
          o[u] = (j < N_OUT) ? (_Float16)P.Wp[(i + u) * N_OUT + j] : (_Float16)0.f;
        *(half4*)(Wpt + j * D_IN + i) = o;
      }
      __syncthreads();
    }
  }
  if (phase < 0) { __threadfence(); cooperative_groups::this_grid().sync(); }

  // ===================== P1: proj (384 tile jobs, grid-stride) ===============
  if (phase == -1 || phase == 1) {
    _Float16* Atile = (_Float16*)smem;            // 128x64 = 16 KB
    _Float16* Btile = (_Float16*)(smem + 16384);  // 128x64 = 16 KB
    int wr = w >> 1, wc = w & 1;                  // 4x2 wave grid: 32-row x 64-col
    int chs = l7 ^ l3h;
    for (int job = bid; job < 384; job += 256) {
      const _Float16 *Asrc, *Bsrc;
      int isV = 0, m0, n0, head = 0, mh = 0;
      if (job < 256) {                            // Q/K: h16 @ [Wqt;Wkt]
        m0 = (job >> 3) * 128;
        int ct = job & 7;
        mh = ct >> 1;                             // 0,1: Q heads; 2,3: K heads
        n0 = (ct & 1) * 128;
        Asrc = h16 + (size_t)m0 * D_IN;
        Bsrc = Wqt + (size_t)(ct * 128) * D_IN;   // Wqt/Wkt contiguous
      } else {                                    // VT = Wvt-rows @ h16-rows
        isV = 1;
        int t = job - 256;
        head = t >> 6;
        int tt = t & 63;
        m0 = (tt >> 5) * 128;
        n0 = (tt & 31) * 128;
        Asrc = Wvt + (size_t)head * (D_HID * D_IN) + (size_t)m0 * D_IN;
        Bsrc = h16 + (size_t)n0 * D_IN;
      }
      f32x4 acc[2][4];
#pragma unroll
      for (int i = 0; i < 2; i++)
#pragma unroll
        for (int j = 0; j < 4; j++) acc[i][j] = z4;
      for (int kc = 0; kc < 8; kc++) {
        __syncthreads();
#pragma unroll
        for (int i = 0; i < 2; i++) {
          int g = w * 2 + i;                      // 0..15
          int row = g * 8 + l3h;                  // 0..127
          async_copy16(Asrc + (size_t)row * D_IN + kc * 64 + chs * 8, Atile + g * 512);
          async_copy16(Bsrc + (size_t)row * D_IN + kc * 64 + chs * 8, Btile + g * 512);
        }
        __syncthreads();
#pragma unroll
        for (int kk = 0; kk < 2; kk++) {
          int ch = ((kk * 4 + quad) ^ (cL & 7)) * 8;
          half8 a[2], bf[4];
#pragma unroll
          for (int mt = 0; mt < 2; mt++)
            a[mt] = *(const half8*)(Atile + (wr * 32 + mt * 16 + cL) * 64 + ch);
#pragma unroll
          for (int nt = 0; nt < 4; nt++)
            bf[nt] = *(const half8*)(Btile + (wc * 64 + nt * 16 + cL) * 64 + ch);
#pragma unroll
          for (int mt = 0; mt < 2; mt++)
#pragma unroll
            for (int nt = 0; nt < 4; nt++)
              acc[mt][nt] = __builtin_amdgcn_mfma_f32_16x16x32_f16(a[mt], bf[nt], acc[mt][nt], 0, 0, 0);
        }
      }
      if (!isV) {
        _Float16* Out = (mh < 2 ? Q16 + (size_t)mh * (N_TOK * D_HID)
                                : K16 + (size_t)(mh - 2) * (N_TOK * D_HID));
        const float* bias = (mh < 2 ? P.bq + mh * D_HID : P.bk + (mh - 2) * D_HID);
#pragma unroll
        for (int mt = 0; mt < 2; mt++) {
          int row = m0 + wr * 32 + mt * 16 + quad * 4;
#pragma unroll
          for (int nt = 0; nt < 4; nt++) {
            int colg = n0 + wc * 64 + nt * 16 + cL;
            float bb = bias[colg];
#pragma unroll
            for (int reg = 0; reg < 4; reg++)
              Out[(size_t)(row + reg) * D_HID + colg] = (_Float16)(acc[mt][nt][reg] + bb);
          }
        }
      } else {
        _Float16* VTh = VT16 + (size_t)head * (N_TOK * D_HID);
        const float* bvh = P.bv + head * D_HID;
#pragma unroll
        for (int mt = 0; mt < 2; mt++) {
          int d0r = m0 + wr * 32 + mt * 16 + quad * 4;
          float bvv[4];
#pragma unroll
          for (int reg = 0; reg < 4; reg++) bvv[reg] = bvh[d0r + reg];
#pragma unroll
          for (int nt = 0; nt < 4; nt++) {
            int tok = n0 + wc * 64 + nt * 16 + cL;
#pragma unroll
            for (int reg = 0; reg < 4; reg++)
              VTh[(size_t)(d0r + reg) * N_TOK + tok] = (_Float16)(acc[mt][nt][reg] + bvv[reg]);
          }
        }
      }
    }
  }
  if (phase < 0) { __threadfence(); cooperative_groups::this_grid().sync(); }

  // ===================== P2: attn (256 jobs, one per block) ==================
  // 8 slices (head*4+gs, XCD-pinned) x 32 rowgroups of 128 rows.
  // 8 waves = 4 row-strips(32 rows) x 2 key-halves of dbuf BN=64 K/V tiles.
  // Fixed-shift softmax; key-halves merge additively in epilogue.
  if (phase == -1 || phase == 2) {
    _Float16* Kbuf0 = (_Float16*)smem;            // 32 KB
    _Float16* Kbuf1 = (_Float16*)(smem + 32768);
    _Float16* Vbuf0 = (_Float16*)(smem + 65536);
    _Float16* Vbuf1 = (_Float16*)(smem + 98304);
    _Float16* pb    = (_Float16*)(smem + 131072) + w * (32 * 40);  // 20 KB tot
    float*    LshF  = (float*)(smem + 151552);    // [8][32]

    int sl = bid & 7, head = sl >> 2, gs = sl & 3;
    int q0 = (bid >> 3) * 128;
    int r = w >> 1, c = w & 1;
    int qrow0 = q0 + r * 32;
    int nstart = gs * 1024;

    const _Float16* Qh = Q16 + head * (N_TOK * D_HID);
    const _Float16* Kh = K16 + head * (N_TOK * D_HID);
    const _Float16* Vh = VT16 + head * (N_TOK * D_HID);
    const float* adjh = P.adj + (size_t)head * N_TOK * N_TOK;

    half8 qf[2][8];
#pragma unroll
    for (int mt = 0; mt < 2; mt++)
#pragma unroll
      for (int ks = 0; ks < 8; ks++)
        qf[mt][ks] = *(const half8*)(Qh + (qrow0 + mt * 16 + cL) * D_HID + ks * 32 + quad * 8);

    const float* adjP[2][4];
#pragma unroll
    for (int mt = 0; mt < 2; mt++)
#pragma unroll
      for (int reg = 0; reg < 4; reg++)
        adjP[mt][reg] = adjh + (size_t)(qrow0 + mt * 16 + quad * 4 + reg) * N_TOK
                        + nstart + c * 32 + cL;

    f32x4 acc[2][16];
    f32x4 accl[2];
#pragma unroll
    for (int mt = 0; mt < 2; mt++) {
      accl[mt] = z4;
#pragma unroll
      for (int dt = 0; dt < 16; dt++) acc[mt][dt] = z4;
    }
    half8 onesf;
#pragma unroll
    for (int j = 0; j < 8; j++) onesf[j] = (cL == 0) ? (_Float16)1.0f : (_Float16)0.0f;

    // prologue: stage iter 0 into buf0 (32 K-instrs + 32 V-instrs over 8 waves)
#pragma unroll
    for (int i = 0; i < 4; i++) {
      int g = w * 4 + i;
      int rK = 2 * g + l5;
      int cK = l31 ^ (rK & 7);
      async_copy16(Kh + (size_t)(nstart + rK) * D_HID + cK * 8, Kbuf0 + g * 512);
      int rV = 8 * g + l3h;
      int cV = l7 ^ (rV & 7);
      async_copy16(Vh + (size_t)rV * N_TOK + nstart + cV * 8, Vbuf0 + g * 512);
    }

    for (int it = 0; it < 16; ++it) {
      _Float16* Kb = (it & 1) ? Kbuf1 : Kbuf0;
      _Float16* Vb = (it & 1) ? Vbuf1 : Vbuf0;
      _Float16* Kd = (it & 1) ? Kbuf0 : Kbuf1;
      _Float16* Vd = (it & 1) ? Vbuf0 : Vbuf1;
      __syncthreads();   // drains DMA(it); prev-iter reads of Kd/Vd complete

      float av[2][2][4];
#pragma unroll
      for (int mt = 0; mt < 2; mt++)
#pragma unroll
        for (int reg = 0; reg < 4; reg++)
#pragma unroll
          for (int ct = 0; ct < 2; ct++)
            av[mt][ct][reg] = __builtin_nontemporal_load(adjP[mt][reg] + it * 64 + ct * 16);

      if (it < 15) {
        int n1 = nstart + (it + 1) * 64;
#pragma unroll
        for (int i = 0; i < 4; i++) {
          int g = w * 4 + i;
          int rK = 2 * g + l5;
          int cK = l31 ^ (rK & 7);
          async_copy16(Kh + (size_t)(n1 + rK) * D_HID + cK * 8, Kd + g * 512);
          int rV = 8 * g + l3h;
          int cV = l7 ^ (rV & 7);
          async_copy16(Vh + (size_t)rV * N_TOK + n1 + cV * 8, Vd + g * 512);
        }
      }

      // QK^T over this wave's 32-key half
      f32x4 s[2][2];
#pragma unroll
      for (int mt = 0; mt < 2; mt++)
#pragma unroll
        for (int ct = 0; ct < 2; ct++) s[mt][ct] = z4;
#pragma unroll
      for (int ks = 0; ks < 8; ks++) {
#pragma unroll
        for (int ct = 0; ct < 2; ct++) {
          int rK = c * 32 + ct * 16 + cL;
          int ck = (ks * 4 + quad) ^ (cL & 7);
          half8 kf = *(const half8*)(Kb + rK * 256 + ck * 8);
          s[0][ct] = __builtin_amdgcn_mfma_f32_16x16x32_f16(qf[0][ks], kf, s[0][ct], 0, 0, 0);
          s[1][ct] = __builtin_amdgcn_mfma_f32_16x16x32_f16(qf[1][ks], kf, s[1][ct], 0, 0, 0);
        }
      }

      // fixed-shift exp: p = min(exp(s*adj - 22), 60000)
#pragma unroll
      for (int mt = 0; mt < 2; mt++)
#pragma unroll
        for (int ct = 0; ct < 2; ct++)
#pragma unroll
          for (int reg = 0; reg < 4; reg++) {
            float sc = s[mt][ct][reg] * av[mt][ct][reg];
            float p = __builtin_amdgcn_exp2f(sc * 1.44269504f - 31.7392909f);
            p = fminf(p, 60000.0f);
            pb[(mt * 16 + quad * 4 + reg) * 40 + ct * 16 + cL] = (_Float16)p;
          }

      // PV over the wave's 32 keys (+ row-sum via ones B-frag)
      half8 pa0 = *(const half8*)(pb + cL * 40 + quad * 8);
      half8 pa1 = *(const half8*)(pb + (16 + cL) * 40 + quad * 8);
      accl[0] = __builtin_amdgcn_mfma_f32_16x16x32_f16(pa0, onesf, accl[0], 0, 0, 0);
      accl[1] = __builtin_amdgcn_mfma_f32_16x16x32_f16(pa1, onesf, accl[1], 0, 0, 0);
#pragma unroll
      for (int dt = 0; dt < 16; dt++) {
        int rV = dt * 16 + cL;
        int cvv = (c * 4 + quad) ^ (cL & 7);
        half8 vf = *(const half8*)(Vb + rV * 64 + cvv * 8);
        acc[0][dt] = __builtin_amdgcn_mfma_f32_16x16x32_f16(pa0, vf, acc[0][dt], 0, 0, 0);
        acc[1][dt] = __builtin_amdgcn_mfma_f32_16x16x32_f16(pa1, vf, acc[1][dt], 0, 0, 0);
      }
    }

    // epilogue: additive c-merge (Osh aliases dead K bufs), store Op + Lp
    __syncthreads();
    _Float16* OshH = (_Float16*)smem;             // [128][256] fp16 = 64 KB
    if (c == 1) {
#pragma unroll
      for (int mt = 0; mt < 2; mt++)
#pragma unroll
        for (int reg = 0; reg < 4; reg++) {
          int row = mt * 16 + quad * 4 + reg;
#pragma unroll
          for (int dt = 0; dt < 16; dt++)
            OshH[(r * 32 + row) * 256 + dt * 16 + cL] = (_Float16)acc[mt][dt][reg];
        }
    }
    if (cL == 0) {
#pragma unroll
      for (int mt = 0; mt < 2; mt++)
#pragma unroll
        for (int reg = 0; reg < 4; reg++)
          LshF[w * 32 + mt * 16 + quad * 4 + reg] = accl[mt][reg];
    }
    __syncthreads();
    if (c == 0) {
#pragma unroll
      for (int mt = 0; mt < 2; mt++)
#pragma unroll
        for (int reg = 0; reg < 4; reg++) {
          int row = mt * 16 + quad * 4 + reg;
          float l = LshF[(r * 2) * 32 + row] + LshF[(r * 2 + 1) * 32 + row];
          float inv = 1.0f / fmaxf(l, 1e-30f);
          int grow = sl * N_TOK + qrow0 + row;
#pragma unroll
          for (int dt = 0; dt < 16; dt++) {
            float o = acc[mt][dt][reg] + (float)OshH[(r * 32 + row) * 256 + dt * 16 + cL];
            Op[(size_t)grow * D_HID + dt * 16 + cL] = (_Float16)(o * inv);
          }
          if (cL == 0) Lp[grow] = l;
        }
    }
  }
  if (phase < 0) { __threadfence(); cooperative_groups::this_grid().sync(); }

  // ===================== P3: final (merge + Wo + LN + Wp + softmax) ==========
  if (phase == -1 || phase == 3) {
    _Float16* Btile = (_Float16*)smem;            // [512][64] = 64 KB
    _Float16* Mlds  = (_Float16*)(smem + 65536);  // [16][520]
    float* outs  = (float*)(smem + 82176);        // [16][48]
    float* lnsum = (float*)(smem + 85248);        // [8][16]
    float* lnsq  = (float*)(smem + 85760);
    float* smx   = (float*)(smem + 86272);
    float* srl   = (float*)(smem + 86336);

    int rowbase = bid * 16;
    int zrow = rowbase + cL;

    // merge fold: af = Sum_s wgt[h][s] * Op_s (Op pre-normalized per slice)
    float wgt[2][4];
#pragma unroll
    for (int hh = 0; hh < 2; hh++) {
      float ls = 0.f, lv[4];
#pragma unroll
      for (int s = 0; s < 4; s++) { lv[s] = Lp[(hh * 4 + s) * N_TOK + zrow]; ls += lv[s]; }
      float inv = 1.0f / fmaxf(ls, 1e-30f);
#pragma unroll
      for (int s = 0; s < 4; s++) wgt[hh][s] = lv[s] * inv;
    }
    half8 af[16];
#pragma unroll
    for (int t = 0; t < 16; t++) {
      int hh = t >> 3;
      int dcol = (t & 7) * 32 + quad * 8;
      float a8[8] = {0, 0, 0, 0, 0, 0, 0, 0};
#pragma unroll
      for (int s = 0; s < 4; s++) {
        half8 o = *(const half8*)(Op + ((size_t)((hh * 4 + s) * N_TOK + zrow)) * D_HID + dcol);
        float wv = wgt[hh][s];
#pragma unroll
        for (int j = 0; j < 8; j++) a8[j] += wv * (float)o[j];
      }
      half8 v;
#pragma unroll
      for (int j = 0; j < 8; j++) v[j] = (_Float16)a8[j];
      af[t] = v;
    }

    f32x4 acc[4];
#pragma unroll
    for (int i = 0; i < 4; i++) acc[i] = z4;
    int chs = l7 ^ l3h;
    for (int kc = 0; kc < 8; kc++) {
      __syncthreads();
#pragma unroll
      for (int i = 0; i < 8; i++) {
        int g = w * 8 + i;                        // 0..63
        int row = g * 8 + l3h;                    // 0..511
        async_copy16(Wot + (size_t)row * D_IN + kc * 64 + chs * 8, Btile + g * 512);
      }
      __syncthreads();
#pragma unroll
      for (int kk = 0; kk < 2; kk++) {
        int ch = ((kk * 4 + quad) ^ (cL & 7)) * 8;
        half8 a = af[kc * 2 + kk];
        half8 bf[4];
#pragma unroll
        for (int nt = 0; nt < 4; nt++)
          bf[nt] = *(const half8*)(Btile + (w * 64 + nt * 16 + cL) * 64 + ch);
#pragma unroll
        for (int nt = 0; nt < 4; nt++)
          acc[nt] = __builtin_amdgcn_mfma_f32_16x16x32_f16(a, bf[nt], acc[nt], 0, 0, 0);
      }
    }

    float sum[4] = {0, 0, 0, 0}, sq[4] = {0, 0, 0, 0};
#pragma unroll
    for (int nt = 0; nt < 4; nt++) {
      int col = w * 64 + nt * 16 + cL;
      float bb = P.bo[col];
#pragma unroll
      for (int reg = 0; reg < 4; reg++) {
        float z = acc[nt][reg] + bb;
        acc[nt][reg] = z;
        sum[reg] += z;
        sq[reg] += z * z;
      }
    }
#pragma unroll
    for (int reg = 0; reg < 4; reg++) {
#pragma unroll
      for (int msk = 1; msk < 16; msk <<= 1) {
        sum[reg] += __shfl_xor(sum[reg], msk, 16);
        sq[reg]  += __shfl_xor(sq[reg], msk, 16);
      }
    }
    if (cL == 0) {
#pragma unroll
      for (int reg = 0; reg < 4; reg++) {
        lnsum[w * 16 + quad * 4 + reg] = sum[reg];
        lnsq[w * 16 + quad * 4 + reg]  = sq[reg];
      }
    }
    __syncthreads();
    float mean[4], rstd[4];
#pragma unroll
    for (int reg = 0; reg < 4; reg++) {
      int row = quad * 4 + reg;
      float ssm = 0.f, s2 = 0.f;
#pragma unroll
      for (int ww = 0; ww < 8; ww++) { ssm += lnsum[ww * 16 + row]; s2 += lnsq[ww * 16 + row]; }
      float mu = ssm * (1.0f / 512.0f);
      float var = s2 * (1.0f / 512.0f) - mu * mu;
      mean[reg] = mu;
      rstd[reg] = rsqrtf(var + 1e-5f);
    }
#pragma unroll
    for (int nt = 0; nt < 4; nt++) {
      int col = w * 64 + nt * 16 + cL;
      float g = P.gamma[col], be = P.beta[col];
#pragma unroll
      for (int reg = 0; reg < 4; reg++) {
        float mval = (acc[nt][reg] - mean[reg]) * rstd[reg] * g + be;
        Mlds[(quad * 4 + reg) * 520 + col] = (_Float16)mval;
      }
    }
    __syncthreads();
    if (w < 3) {
      f32x4 a2 = z4;
#pragma unroll
      for (int t = 0; t < 16; t++) {
        half8 am = *(const half8*)(Mlds + cL * 520 + t * 32 + quad * 8);
        half8 bm = *(const half8*)(Wpt + (w * 16 + cL) * D_IN + t * 32 + quad * 8);
        a2 = __builtin_amdgcn_mfma_f32_16x16x32_f16(am, bm, a2, 0, 0, 0);
      }
      int col = w * 16 + cL;
      float bpv = (col < N_OUT) ? P.bp[col] : 0.0f;
#pragma unroll
      for (int reg = 0; reg < 4; reg++)
        outs[(quad * 4 + reg) * 48 + col] = a2[reg] + bpv;
    }
    __syncthreads();
    if (tid < 16) {
      int row = tid;
      float mx = -1e30f;
      for (int j = 0; j < N_OUT; j++) mx = fmaxf(mx, outs[row * 48 + j]);
      float ssum = 0.f;
      for (int j = 0; j < N_OUT; j++) ssum += __expf(outs[row * 48 + j] - mx);
      smx[row] = mx;
      srl[row] = 1.0f / ssum;
    }
    __syncthreads();
#pragma unroll
    for (int i = 0; i < 2; i++) {
      int lin = tid + 512 * i;                    // 0..639 = 16 rows x 40 cols
      if (lin < 16 * N_OUT) {
        int row = lin / N_OUT, col = lin % N_OUT;
        P.out[(size_t)(rowbase + row) * N_OUT + col] =
            __expf(outs[row * 48 + col] - smx[row]) * srl[row];
      }
    }
  }
}

extern "C" void kernel_launch(void* const* d_in, const int* in_sizes, int n_in,
                              void* d_out, int out_size, void* d_ws, size_t ws_size,
                              hipStream_t stream)
{
  Params P;
  P.adj   = (const float*)d_in[0];
  P.h     = (const float*)d_in[1];
  P.Wq    = (const float*)d_in[2];
  P.bq    = (const float*)d_in[3];
  P.Wk    = (const float*)d_in[4];
  P.bk    = (const float*)d_in[5];
  P.Wv    = (const float*)d_in[6];
  P.bv    = (const float*)d_in[7];
  P.Wo    = (const float*)d_in[8];
  P.bo    = (const float*)d_in[9];
  P.gamma = (const float*)d_in[10];
  P.beta  = (const float*)d_in[11];
  P.Wp    = (const float*)d_in[12];
  P.bp    = (const float*)d_in[13];
  P.out   = (float*)d_out;
  P.ws    = (char*)d_ws;

  // Try single cooperative launch (1 block/CU co-residency); fall back to
  // 4 regular phase launches if unsupported/rejected.
  bool coop_ok = false;
  int dev = 0, attr = 0;
  if (hipGetDevice(&dev) == hipSuccess &&
      hipDeviceGetAttribute(&attr, hipDeviceAttributeCooperativeLaunch, dev) == hipSuccess &&
      attr) {
    int maxBlocks = 0;
    if (hipOccupancyMaxActiveBlocksPerMultiprocessor(
            &maxBlocks, (const void*)fused_kernel, 512, 0) == hipSuccess &&
        maxBlocks >= 1) {
      int phase = -1;
      void* args[] = { &P, &phase };
      hipError_t e = hipLaunchCooperativeKernel((const void*)fused_kernel,
                                                dim3(256), dim3(512), args, 0, stream);
      if (e == hipSuccess) coop_ok = true;
    }
  }
  if (!coop_ok) {
    (void)hipGetLastError();   // clear any launch-rejection error state
    fused_kernel<<<256, 512, 0, stream>>>(P, 0);
    fused_kernel<<<256, 512, 0, stream>>>(P, 1);
    fused_kernel<<<256, 512, 0, stream>>>(P, 2);
    fused_kernel<<<256, 512, 0, stream>>>(P, 3);
  }
}

// Round 9
// 299.860 us; speedup vs baseline: 1.2818x; 1.2818x over previous
//
#include <hip/hip_runtime.h>
#include <hip/hip_cooperative_groups.h>

#define N_TOK 4096
#define D_IN  512
#define D_HID 256
#define N_OUT 40

typedef _Float16 half8 __attribute__((ext_vector_type(8)));
typedef _Float16 half4 __attribute__((ext_vector_type(4)));
typedef float    f32x4 __attribute__((ext_vector_type(4)));

// async 16B/lane global->LDS DMA; lds dst is wave-uniform base (+lane*16 implicit)
__device__ __forceinline__ void async_copy16(const _Float16* g, _Float16* l) {
  __builtin_amdgcn_global_load_lds(
      (const __attribute__((address_space(1))) unsigned int*)(g),
      (__attribute__((address_space(3))) unsigned int*)(l), 16, 0, 0);
}

struct Params {
  const float *adj, *h, *Wq, *bq, *Wk, *bk, *Wv, *bv, *Wo, *bo, *gamma, *beta, *Wp, *bp;
  float* out;
  char* ws;
};

// workspace offsets (bytes), R4 layout. h16/Wqt/Wkt/Wvt overlay Op (dead after P1).
#define OFF_WOT   0u
#define OFF_WPT   524288u
#define OFF_Q16   573440u
#define OFF_K16   4767744u
#define OFF_VT16  8962048u
#define OFF_MP    13156352u
#define OFF_LP    13287424u
#define OFF_OP    17612800u
#define OFF_H16   17612800u
#define OFF_WQT   21807104u
#define OFF_WKT   22331392u
#define OFF_WVT   22855680u

// phase: -1 = all phases with grid.sync (cooperative); 0..3 = single phase.
// 256-thr blocks: compiler allocates full VGPRs (R3 attn = 120, no spill);
// 512-thr blocks were hard-capped at 128 and spilled (R7/R8 post-mortem).
__global__ __launch_bounds__(256, 2) void fused_kernel(Params P, int phase)
{
  __shared__ __align__(16) char smem[74752];   // == R3 attn LDS, proven 2 blocks/CU
  const int bid = blockIdx.x, tid = threadIdx.x;
  const int w = tid >> 6, lane = tid & 63, quad = lane >> 4, cL = lane & 15;
  const f32x4 z4 = {0.f, 0.f, 0.f, 0.f};

  char* ws = P.ws;
  _Float16* Wot  = (_Float16*)(ws + OFF_WOT);
  _Float16* Wpt  = (_Float16*)(ws + OFF_WPT);
  _Float16* Q16  = (_Float16*)(ws + OFF_Q16);
  _Float16* K16  = (_Float16*)(ws + OFF_K16);
  _Float16* VT16 = (_Float16*)(ws + OFF_VT16);
  float*    Mp   = (float*)   (ws + OFF_MP);
  float*    Lp   = (float*)   (ws + OFF_LP);
  _Float16* Op   = (_Float16*)(ws + OFF_OP);
  _Float16* h16  = (_Float16*)(ws + OFF_H16);
  _Float16* Wqt  = (_Float16*)(ws + OFF_WQT);
  _Float16* Wkt  = (_Float16*)(ws + OFF_WKT);
  _Float16* Wvt  = (_Float16*)(ws + OFF_WVT);

  // ===================== P0: prep (grid-stride over 1304 jobs) ===============
  if (phase == -1 || phase == 0) {
    float* lds = (float*)smem;                 // 64x65 floats = 16.6 KB
    for (int job = bid; job < 1304; job += 512) {
      if (job < 1024) {                        // h -> h16 (4096x512)
        int base = job * 2048 + tid * 8;
        float4 x0 = *(const float4*)(P.h + base);
        float4 x1 = *(const float4*)(P.h + base + 4);
        half8 o;
        o[0]=(_Float16)x0.x; o[1]=(_Float16)x0.y; o[2]=(_Float16)x0.z; o[3]=(_Float16)x0.w;
        o[4]=(_Float16)x1.x; o[5]=(_Float16)x1.y; o[6]=(_Float16)x1.z; o[7]=(_Float16)x1.w;
        *(half8*)(h16 + base) = o;
      } else if (job < 1280) {                 // W transposes via 64x64 LDS tile
        const float* src; _Float16* dst; int in_nc, i0, d0;
        if (job < 1216) {                      // Wq/Wk/Wv: 6 mats x 32 tiles
          int t = job - 1024;
          int mat = t >> 5;
          int m = mat >> 1, head = mat & 1;
          src = (m==0 ? P.Wq : (m==1 ? P.Wk : P.Wv)) + head * (D_IN * D_HID);
          dst = (m==0 ? Wqt : (m==1 ? Wkt : Wvt)) + head * (D_IN * D_HID);
          in_nc = D_HID;
          int tt = t & 31;
          i0 = (tt >> 2) * 64; d0 = (tt & 3) * 64;
        } else {                               // Wo: 64 tiles
          int t = job - 1216;
          src = P.Wo; dst = Wot; in_nc = D_IN;
          i0 = (t >> 3) * 64; d0 = (t & 7) * 64;
        }
        int l15 = tid & 15, l4 = tid >> 4;
#pragma unroll
        for (int p = 0; p < 4; p++) {
          int ii = p * 16 + l4;
          float4 x = *(const float4*)(src + (size_t)(i0 + ii) * in_nc + d0 + l15 * 4);
          lds[(l15 * 4 + 0) * 65 + ii] = x.x;
          lds[(l15 * 4 + 1) * 65 + ii] = x.y;
          lds[(l15 * 4 + 2) * 65 + ii] = x.z;
          lds[(l15 * 4 + 3) * 65 + ii] = x.w;
        }
        __syncthreads();
        int dd = tid >> 2, chunk = tid & 3;
        half8 o0, o1;
#pragma unroll
        for (int j = 0; j < 8; j++) o0[j] = (_Float16)lds[dd * 65 + chunk * 16 + j];
#pragma unroll
        for (int j = 0; j < 8; j++) o1[j] = (_Float16)lds[dd * 65 + chunk * 16 + 8 + j];
        *(half8*)(dst + (size_t)(d0 + dd) * D_IN + i0 + chunk * 16) = o0;
        *(half8*)(dst + (size_t)(d0 + dd) * D_IN + i0 + chunk * 16 + 8) = o1;
      } else {                                 // Wp transpose+pad [48][512]
        int blk = job - 1280;                  // 0..23
        int idx = blk * 1024 + tid * 4;
        int j = idx >> 9, i = idx & 511;
        half4 o;
#pragma unroll
        for (int u = 0; u < 4; u++)
          o[u] = (j < N_OUT) ? (_Float16)P.Wp[(i + u) * N_OUT + j] : (_Float16)0.f;
        *(half4*)(Wpt + j * D_IN + i) = o;
      }
      __syncthreads();                         // lds reuse across trips
    }
  }
  if (phase < 0) { __threadfence(); cooperative_groups::this_grid().sync(); }

  // ===================== P1: proj (R4 verbatim, 384 active blocks) ===========
  if ((phase == -1 || phase == 1) && bid < 384) {
    _Float16* Atile = (_Float16*)smem;            // 128x64 = 16 KB
    _Float16* Btile = (_Float16*)(smem + 16384);  // 128x64 = 16 KB
    int wr = w >> 1, wc = w & 1;
    const _Float16 *Asrc, *Bsrc;
    int isV = 0, m0, n0, head = 0, mh = 0;
    if (bid < 256) {
      m0 = (bid >> 3) * 128;
      int ct = bid & 7;
      mh = ct >> 1;
      n0 = (ct & 1) * 128;
      Asrc = h16 + (size_t)m0 * D_IN;
      Bsrc = Wqt + (size_t)(ct * 128) * D_IN;     // Wqt/Wkt contiguous
    } else {
      isV = 1;
      int t = bid - 256;
      head = t >> 6;
      int tt = t & 63;
      m0 = (tt >> 5) * 128;
      n0 = (tt & 31) * 128;
      Asrc = Wvt + (size_t)head * (D_HID * D_IN) + (size_t)m0 * D_IN;
      Bsrc = h16 + (size_t)n0 * D_IN;
    }
    f32x4 acc[4][4];
#pragma unroll
    for (int i = 0; i < 4; i++)
#pragma unroll
      for (int j = 0; j < 4; j++) acc[i][j] = z4;
    int r8 = lane >> 3, chs = (lane & 7) ^ r8;
    for (int kc = 0; kc < 8; kc++) {
      __syncthreads();
#pragma unroll
      for (int g = 0; g < 4; g++) {
        int row = (w * 4 + g) * 8 + r8;
        async_copy16(Asrc + (size_t)row * D_IN + kc * 64 + chs * 8, Atile + (w * 4 + g) * 512);
        async_copy16(Bsrc + (size_t)row * D_IN + kc * 64 + chs * 8, Btile + (w * 4 + g) * 512);
      }
      __syncthreads();
#pragma unroll
      for (int kk = 0; kk < 2; kk++) {
        int ch = ((kk * 4 + quad) ^ (cL & 7)) * 8;
        half8 a[4], bf[4];
#pragma unroll
        for (int mt = 0; mt < 4; mt++)
          a[mt] = *(const half8*)(Atile + (wr * 64 + mt * 16 + cL) * 64 + ch);
#pragma unroll
        for (int nt = 0; nt < 4; nt++)
          bf[nt] = *(const half8*)(Btile + (wc * 64 + nt * 16 + cL) * 64 + ch);
#pragma unroll
        for (int mt = 0; mt < 4; mt++)
#pragma unroll
          for (int nt = 0; nt < 4; nt++)
            acc[mt][nt] = __builtin_amdgcn_mfma_f32_16x16x32_f16(a[mt], bf[nt], acc[mt][nt], 0, 0, 0);
      }
    }
    if (!isV) {
      _Float16* Out = (mh < 2 ? Q16 + (size_t)mh * (N_TOK * D_HID)
                              : K16 + (size_t)(mh - 2) * (N_TOK * D_HID));
      const float* bias = (mh < 2 ? P.bq + mh * D_HID : P.bk + (mh - 2) * D_HID);
#pragma unroll
      for (int mt = 0; mt < 4; mt++) {
        int row = m0 + wr * 64 + mt * 16 + quad * 4;
#pragma unroll
        for (int nt = 0; nt < 4; nt++) {
          int colg = n0 + wc * 64 + nt * 16 + cL;
          float bb = bias[colg];
#pragma unroll
          for (int reg = 0; reg < 4; reg++)
            Out[(size_t)(row + reg) * D_HID + colg] = (_Float16)(acc[mt][nt][reg] + bb);
        }
      }
    } else {
      _Float16* VTh = VT16 + (size_t)head * (N_TOK * D_HID);
      const float* bvh = P.bv + head * D_HID;
#pragma unroll
      for (int mt = 0; mt < 4; mt++) {
        int d0r = m0 + wr * 64 + mt * 16 + quad * 4;
        float bvv[4];
#pragma unroll
        for (int reg = 0; reg < 4; reg++) bvv[reg] = bvh[d0r + reg];
#pragma unroll
        for (int nt = 0; nt < 4; nt++) {
          int tok = n0 + wc * 64 + nt * 16 + cL;
#pragma unroll
          for (int reg = 0; reg < 4; reg++)
            VTh[(size_t)(d0r + reg) * N_TOK + tok] = (_Float16)(acc[mt][nt][reg] + bvv[reg]);
        }
      }
    }
  }
  if (phase < 0) { __threadfence(); cooperative_groups::this_grid().sync(); }

  // ===================== P2: attn (R3 verbatim: 86 us proven) ================
  // grid 512 = 2 heads x 4 KV-splits x 64 rowgroups of 64 rows; 4 waves;
  // single-buffered K/V staging via global_load_lds; online softmax.
  if (phase == -1 || phase == 2) {
    _Float16* Ktile  = (_Float16*)smem;             // 64x256 = 32 KB
    _Float16* VTtile = (_Float16*)(smem + 32768);   // 256x64 = 32 KB
    _Float16* Pbuf   = (_Float16*)(smem + 65536);   // 4 x 16x72 = 9 KB

    int head = (bid >> 2) & 1;
    int gs = bid & 3;
    int q0 = (bid >> 3) * 64;

    const _Float16* Qh = Q16 + head * (N_TOK * D_HID);
    const _Float16* Kh = K16 + head * (N_TOK * D_HID);
    const _Float16* Vh = VT16 + head * (N_TOK * D_HID);
    const float* adjh = P.adj + (size_t)head * N_TOK * N_TOK;

    int qrow = q0 + w * 16;
    int nstart = gs * 1024;

    half8 qf[8];
#pragma unroll
    for (int t = 0; t < 8; t++)
      qf[t] = *(const half8*)(Qh + (qrow + cL) * D_HID + t * 32 + quad * 8);

    f32x4 acc[16];
#pragma unroll
    for (int i = 0; i < 16; i++) acc[i] = z4;
    float m_i[4] = {-1e30f, -1e30f, -1e30f, -1e30f};
    float l_i[4] = {0.f, 0.f, 0.f, 0.f};

    _Float16* pb = Pbuf + w * (16 * 72);

    const float* adjR[4];
#pragma unroll
    for (int reg = 0; reg < 4; reg++)
      adjR[reg] = adjh + (size_t)(qrow + quad * 4 + reg) * N_TOK + nstart + cL;

    int l5 = lane >> 5, l31 = lane & 31;
    int l3 = lane >> 3, l7 = lane & 7;

    for (int it = 0; it < 16; ++it) {
      int n0 = nstart + it * 64;

      __syncthreads();

#pragma unroll
      for (int i = 0; i < 8; i++) {
        int g = w * 8 + i;
        int rK = 2 * g + l5;
        int cK = l31 ^ (rK & 7);
        async_copy16(Kh + (size_t)(n0 + rK) * D_HID + cK * 8, Ktile + g * 512);
        int rV = g * 8 + l3;
        int cV = l7 ^ (rV & 7);
        async_copy16(Vh + (size_t)rV * N_TOK + n0 + cV * 8, VTtile + g * 512);
      }
      float av[4][4];
#pragma unroll
      for (int reg = 0; reg < 4; reg++)
#pragma unroll
        for (int ct = 0; ct < 4; ct++)
          av[reg][ct] = __builtin_nontemporal_load(adjR[reg] + it * 64 + ct * 16);

      __syncthreads();

      f32x4 s[4];
#pragma unroll
      for (int ct = 0; ct < 4; ct++) s[ct] = z4;
#pragma unroll
      for (int t = 0; t < 8; t++) {
#pragma unroll
        for (int ct = 0; ct < 4; ct++) {
          int rK = ct * 16 + cL;
          int ck = (t * 4 + quad) ^ (rK & 7);
          half8 kf = *(const half8*)(Ktile + rK * 256 + ck * 8);
          s[ct] = __builtin_amdgcn_mfma_f32_16x16x32_f16(qf[t], kf, s[ct], 0, 0, 0);
        }
      }

      float alpha[4];
#pragma unroll
      for (int reg = 0; reg < 4; reg++) {
#pragma unroll
        for (int ct = 0; ct < 4; ct++) s[ct][reg] *= av[reg][ct];
        float mx = fmaxf(fmaxf(s[0][reg], s[1][reg]), fmaxf(s[2][reg], s[3][reg]));
#pragma unroll
        for (int msk = 1; msk < 16; msk <<= 1) mx = fmaxf(mx, __shfl_xor(mx, msk, 16));
        float mnew = fmaxf(m_i[reg], mx);
        alpha[reg] = __expf(m_i[reg] - mnew);
        m_i[reg] = mnew;
        float rs = 0.f;
#pragma unroll
        for (int ct = 0; ct < 4; ct++) {
          float p = __expf(s[ct][reg] - mnew);
          s[ct][reg] = p;
          rs += p;
        }
#pragma unroll
        for (int msk = 1; msk < 16; msk <<= 1) rs += __shfl_xor(rs, msk, 16);
        l_i[reg] = l_i[reg] * alpha[reg] + rs;
      }

#pragma unroll
      for (int reg = 0; reg < 4; reg++)
#pragma unroll
        for (int ct = 0; ct < 4; ct++)
          pb[(quad * 4 + reg) * 72 + ct * 16 + cL] = (_Float16)s[ct][reg];

#pragma unroll
      for (int dt = 0; dt < 16; dt++)
#pragma unroll
        for (int reg = 0; reg < 4; reg++)
          acc[dt][reg] *= alpha[reg];

      half8 pf0 = *(const half8*)(pb + cL * 72 + quad * 8);
      half8 pf1 = *(const half8*)(pb + cL * 72 + 32 + quad * 8);
#pragma unroll
      for (int dt = 0; dt < 16; dt++) {
        int rV = dt * 16 + cL;
        int c0 = (quad) ^ (rV & 7);
        int c1 = (4 + quad) ^ (rV & 7);
        half8 v0 = *(const half8*)(VTtile + rV * 64 + c0 * 8);
        half8 v1 = *(const half8*)(VTtile + rV * 64 + c1 * 8);
        acc[dt] = __builtin_amdgcn_mfma_f32_16x16x32_f16(pf0, v0, acc[dt], 0, 0, 0);
        acc[dt] = __builtin_amdgcn_mfma_f32_16x16x32_f16(pf1, v1, acc[dt], 0, 0, 0);
      }
    }

    int prow = (head * 4 + gs) * N_TOK + qrow + quad * 4;
#pragma unroll
    for (int reg = 0; reg < 4; reg++) {
      int row = prow + reg;
#pragma unroll
      for (int dt = 0; dt < 16; dt++)
        Op[(size_t)row * D_HID + dt * 16 + cL] = (_Float16)acc[dt][reg];
      if (cL == 0) { Mp[row] = m_i[reg]; Lp[row] = l_i[reg]; }
    }
  }
  if (phase < 0) { __threadfence(); cooperative_groups::this_grid().sync(); }

  // ===================== P3: final (merge-fold + Wo + LN + Wp + softmax) =====
  if ((phase == -1 || phase == 3) && bid < 256) {
    _Float16* Btile = (_Float16*)smem;            // [512][64] = 64 KB (GEMM stage)
    _Float16* Mlds  = (_Float16*)smem;            // aliases Btile after GEMM
    float* outs  = (float*)(smem + 66560);        // [16][48]
    float* lnsum = (float*)(smem + 69632);        // [4][16]
    float* lnsq  = (float*)(smem + 69888);
    float* smx   = (float*)(smem + 70144);
    float* srl   = (float*)(smem + 70208);

    int rowbase = bid * 16;
    int zrow = rowbase + cL;

    // merge fold (R4 semantics): wgt[h][s] = exp(m_s - mmax) / Sum f_s*l_s
    float wgt[2][4];
#pragma unroll
    for (int hh = 0; hh < 2; hh++) {
      float m[4], l[4], mm = -1e30f;
#pragma unroll
      for (int s = 0; s < 4; s++) {
        int idx = (hh * 4 + s) * N_TOK + zrow;
        m[s] = Mp[idx]; l[s] = Lp[idx];
        mm = fmaxf(mm, m[s]);
      }
      float f[4], denom = 0.f;
#pragma unroll
      for (int s = 0; s < 4; s++) { f[s] = __expf(m[s] - mm); denom += f[s] * l[s]; }
      float inv = 1.0f / fmaxf(denom, 1e-30f);
#pragma unroll
      for (int s = 0; s < 4; s++) wgt[hh][s] = f[s] * inv;
    }
    half8 af[16];
#pragma unroll
    for (int t = 0; t < 16; t++) {
      int hh = t >> 3;
      int dcol = (t & 7) * 32 + quad * 8;
      float a8[8] = {0, 0, 0, 0, 0, 0, 0, 0};
#pragma unroll
      for (int s = 0; s < 4; s++) {
        half8 o = *(const half8*)(Op + ((size_t)((hh * 4 + s) * N_TOK + zrow)) * D_HID + dcol);
        float wv = wgt[hh][s];
#pragma unroll
        for (int j = 0; j < 8; j++) a8[j] += wv * (float)o[j];
      }
      half8 v;
#pragma unroll
      for (int j = 0; j < 8; j++) v[j] = (_Float16)a8[j];
      af[t] = v;
    }

    f32x4 acc[8];
#pragma unroll
    for (int i = 0; i < 8; i++) acc[i] = z4;
    int r8 = lane >> 3, chs = (lane & 7) ^ r8;
    for (int kc = 0; kc < 8; kc++) {
      __syncthreads();
#pragma unroll
      for (int g = 0; g < 16; g++) {
        int row = (w * 16 + g) * 8 + r8;
        async_copy16(Wot + (size_t)row * D_IN + kc * 64 + chs * 8, Btile + (w * 16 + g) * 512);
      }
      __syncthreads();
#pragma unroll
      for (int kk = 0; kk < 2; kk++) {
        int ch = ((kk * 4 + quad) ^ (cL & 7)) * 8;
        half8 a = af[kc * 2 + kk];
        half8 bf[8];
#pragma unroll
        for (int nt = 0; nt < 8; nt++)
          bf[nt] = *(const half8*)(Btile + (w * 128 + nt * 16 + cL) * 64 + ch);
#pragma unroll
        for (int nt = 0; nt < 8; nt++)
          acc[nt] = __builtin_amdgcn_mfma_f32_16x16x32_f16(a, bf[nt], acc[nt], 0, 0, 0);
      }
    }

    float sum[4] = {0, 0, 0, 0}, sq[4] = {0, 0, 0, 0};
#pragma unroll
    for (int nt = 0; nt < 8; nt++) {
      int col = w * 128 + nt * 16 + cL;
      float bb = P.bo[col];
#pragma unroll
      for (int reg = 0; reg < 4; reg++) {
        float z = acc[nt][reg] + bb;
        acc[nt][reg] = z;
        sum[reg] += z;
        sq[reg] += z * z;
      }
    }
#pragma unroll
    for (int reg = 0; reg < 4; reg++) {
#pragma unroll
      for (int msk = 1; msk < 16; msk <<= 1) {
        sum[reg] += __shfl_xor(sum[reg], msk, 16);
        sq[reg]  += __shfl_xor(sq[reg], msk, 16);
      }
    }
    if (cL == 0) {
#pragma unroll
      for (int reg = 0; reg < 4; reg++) {
        lnsum[w * 16 + quad * 4 + reg] = sum[reg];
        lnsq[w * 16 + quad * 4 + reg]  = sq[reg];
      }
    }
    __syncthreads();
    float mean[4], rstd[4];
#pragma unroll
    for (int reg = 0; reg < 4; reg++) {
      int row = quad * 4 + reg;
      float ssm = lnsum[row] + lnsum[16 + row] + lnsum[32 + row] + lnsum[48 + row];
      float s2  = lnsq[row]  + lnsq[16 + row]  + lnsq[32 + row]  + lnsq[48 + row];
      float mu = ssm * (1.0f / 512.0f);
      float var = s2 * (1.0f / 512.0f) - mu * mu;
      mean[reg] = mu;
      rstd[reg] = rsqrtf(var + 1e-5f);
    }
    // Btile dead; Mlds aliases it
#pragma unroll
    for (int nt = 0; nt < 8; nt++) {
      int col = w * 128 + nt * 16 + cL;
      float g = P.gamma[col], be = P.beta[col];
#pragma unroll
      for (int reg = 0; reg < 4; reg++) {
        float mval = (acc[nt][reg] - mean[reg]) * rstd[reg] * g + be;
        Mlds[(quad * 4 + reg) * 520 + col] = (_Float16)mval;
      }
    }
    __syncthreads();
    if (w < 3) {
      f32x4 a2 = z4;
#pragma unroll
      for (int t = 0; t < 16; t++) {
        half8 am = *(const half8*)(Mlds + cL * 520 + t * 32 + quad * 8);
        half8 bm = *(const half8*)(Wpt + (w * 16 + cL) * D_IN + t * 32 + quad * 8);
        a2 = __builtin_amdgcn_mfma_f32_16x16x32_f16(am, bm, a2, 0, 0, 0);
      }
      int col = w * 16 + cL;
      float bpv = (col < N_OUT) ? P.bp[col] : 0.0f;
#pragma unroll
      for (int reg = 0; reg < 4; reg++)
        outs[(quad * 4 + reg) * 48 + col] = a2[reg] + bpv;
    }
    __syncthreads();
    if (tid < 16) {
      int row = tid;
      float mx = -1e30f;
      for (int j = 0; j < N_OUT; j++) mx = fmaxf(mx, outs[row * 48 + j]);
      float ssum = 0.f;
      for (int j = 0; j < N_OUT; j++) ssum += __expf(outs[row * 48 + j] - mx);
      smx[row] = mx;
      srl[row] = 1.0f / ssum;
    }
    __syncthreads();
#pragma unroll
    for (int i = 0; i < 3; i++) {
      int lin = tid + 256 * i;                  // 0..639 = 16 rows x 40 cols
      if (lin < 16 * N_OUT) {
        int row = lin / N_OUT, col = lin % N_OUT;
        P.out[(size_t)(rowbase + row) * N_OUT + col] =
            __expf(outs[row * 48 + col] - smx[row]) * srl[row];
      }
    }
  }
}

extern "C" void kernel_launch(void* const* d_in, const int* in_sizes, int n_in,
                              void* d_out, int out_size, void* d_ws, size_t ws_size,
                              hipStream_t stream)
{
  Params P;
  P.adj   = (const float*)d_in[0];
  P.h     = (const float*)d_in[1];
  P.Wq    = (const float*)d_in[2];
  P.bq    = (const float*)d_in[3];
  P.Wk    = (const float*)d_in[4];
  P.bk    = (const float*)d_in[5];
  P.Wv    = (const float*)d_in[6];
  P.bv    = (const float*)d_in[7];
  P.Wo    = (const float*)d_in[8];
  P.bo    = (const float*)d_in[9];
  P.gamma = (const float*)d_in[10];
  P.beta  = (const float*)d_in[11];
  P.Wp    = (const float*)d_in[12];
  P.bp    = (const float*)d_in[13];
  P.out   = (float*)d_out;
  P.ws    = (char*)d_ws;

  // Single cooperative launch needs 2 blocks/CU co-residency (grid 512 on
  // 256 CUs). Verify with the occupancy API; otherwise 4 plain phase launches.
  bool coop_ok = false;
  int dev = 0, attr = 0;
  if (hipGetDevice(&dev) == hipSuccess &&
      hipDeviceGetAttribute(&attr, hipDeviceAttributeCooperativeLaunch, dev) == hipSuccess &&
      attr) {
    int maxBlocks = 0;
    if (hipOccupancyMaxActiveBlocksPerMultiprocessor(
            &maxBlocks, (const void*)fused_kernel, 256, 0) == hipSuccess &&
        maxBlocks >= 2) {
      int phase = -1;
      void* args[] = { &P, &phase };
      hipError_t e = hipLaunchCooperativeKernel((const void*)fused_kernel,
                                                dim3(512), dim3(256), args, 0, stream);
      if (e == hipSuccess) coop_ok = true;
    }
  }
  if (!coop_ok) {
    (void)hipGetLastError();   // clear any launch-rejection error state
    fused_kernel<<<512, 256, 0, stream>>>(P, 0);
    fused_kernel<<<512, 256, 0, stream>>>(P, 1);
    fused_kernel<<<512, 256, 0, stream>>>(P, 2);
    fused_kernel<<<512, 256, 0, stream>>>(P, 3);
  }
}